// Round 3
// baseline (592.003 us; speedup 1.0000x reference)
//
#include <hip/hip_runtime.h>

// Problem constants (fixed by setup_inputs)
#define BB 2
#define CC 256
#define HH 100
#define WW 100
#define NROI 512
#define KDIM 12544   // 49*256
#define FC 1024

typedef _Float16 half_t;
typedef _Float16 f16x2 __attribute__((ext_vector_type(2)));
typedef _Float16 f16x8 __attribute__((ext_vector_type(8)));
typedef _Float16 f16x4 __attribute__((ext_vector_type(4)));
typedef float f32x4 __attribute__((ext_vector_type(4)));

// ---------------- feat (B,C,H,W) fp32 -> featT (B,H*W,C) fp16 ----------------
__global__ __launch_bounds__(256) void transpose_feat(const float* __restrict__ feat,
                                                      half_t* __restrict__ featT) {
  __shared__ float tile[32][33];
  int b = blockIdx.z;
  int hw0 = blockIdx.x * 32;
  int c0 = blockIdx.y * 32;
  int tx = threadIdx.x, ty = threadIdx.y;
  const float* fb = feat + (size_t)b * CC * (HH * WW);
#pragma unroll
  for (int i = 0; i < 4; i++) {
    int c = c0 + ty + i * 8;
    int hw = hw0 + tx;
    tile[ty + i * 8][tx] = (hw < HH * WW) ? fb[(size_t)c * (HH * WW) + hw] : 0.0f;
  }
  __syncthreads();
  half_t* ob = featT + (size_t)b * (HH * WW) * CC;
#pragma unroll
  for (int i = 0; i < 4; i++) {
    int hw = hw0 + ty + i * 8;
    int c = c0 + tx;
    if (hw < HH * WW) ob[(size_t)hw * CC + c] = (half_t)tile[tx][ty + i * 8];
  }
}

// ---- w1 (1024, 12544 with k=c*49+p) -> w1p fp16 (1024, 12544 with k'=p*256+c) ----
__global__ __launch_bounds__(256) void permute_w1(const float* __restrict__ w1,
                                                  half_t* __restrict__ w1p) {
  __shared__ float row[KDIM];  // 50176 B
  int j = blockIdx.x;
  const float* src = w1 + (size_t)j * KDIM;
  for (int i = threadIdx.x; i < KDIM; i += 256) row[i] = src[i];
  __syncthreads();
  half_t* dst = w1p + (size_t)j * KDIM;
  for (int o = threadIdx.x; o < KDIM; o += 256) {
    int c = o & 255, p = o >> 8;
    dst[o] = (half_t)row[c * 49 + p];   // LDS stride 49 -> odd bank stride, conflict-free
  }
}

// ---------------- fp32 -> fp16 convert (w2) ----------------
__global__ __launch_bounds__(256) void convert_f32_f16(const float* __restrict__ in,
                                                       half_t* __restrict__ out, int n) {
  int i4 = (blockIdx.x * 256 + threadIdx.x) * 4;
  if (i4 < n) {
    float4 v = *(const float4*)(in + i4);
    f16x4 o;
    o[0] = (half_t)v.x; o[1] = (half_t)v.y; o[2] = (half_t)v.z; o[3] = (half_t)v.w;
    *(f16x4*)(out + i4) = o;
  }
}

// ---------------- deformable PSROI pooling, one block per ROI ----------------
// Phase 1: 49 bins x 16 samples -> 4 (idx, weight) corners each, into LDS.
// Phase 2: thread owns channel pair (half2 loads); bins split odd/even across
//          thread halves; broadcast LDS reads for metadata.
// Phase 3 (PASS2): LDS-staged transpose so the (N,C,7,7) output write is a
//          fully-coalesced float4 stream (kills 7.7x HBM write amplification).
template <bool PASS2>
__global__ __launch_bounds__(256) void pool_kernel(const half_t* __restrict__ featT,
                                                   const float* __restrict__ rois,
                                                   const float* __restrict__ om,
                                                   half_t* __restrict__ xout,
                                                   float* __restrict__ out) {
  struct Corner { int idx; float w; };
  __shared__ Corner s_c[784 * 4];              // 25088 B
  __shared__ float s_vld[784];                 //  3136 B
  __shared__ float s_scale[49];
  __shared__ float s_out[PASS2 ? 12544 : 4];   // 50176 B (PASS2 only)

  const int n = blockIdx.x;
  const int tid = threadIdx.x;
  const float* r = rois + n * 5;
  const int b = (int)r[0];
  const float rsw = rintf(r[1]) * 0.0625f - 0.5f;   // rintf = round-half-even = jnp.round
  const float rsh = rintf(r[2]) * 0.0625f - 0.5f;
  const float rew = (rintf(r[3]) + 1.0f) * 0.0625f - 0.5f;
  const float reh = (rintf(r[4]) + 1.0f) * 0.0625f - 0.5f;
  const float roi_w = fmaxf(rew - rsw, 0.1f);
  const float roi_h = fmaxf(reh - rsh, 0.1f);
  const float bin_h = roi_h / 7.0f, bin_w = roi_w / 7.0f;
  const float sub_h = bin_h * 0.25f, sub_w = bin_w * 0.25f;
  const half_t* fb = featT + (size_t)b * (HH * WW) * CC;

  // ---- phase 1: sample metadata ----
  for (int si = tid; si < 784; si += 256) {
    int p = si >> 4, s = si & 15;
    int ph = p / 7, pw = p - ph * 7;
    float tx = 0.0f, ty = 0.0f;
    if (PASS2) {
      // part_h = floor(ph/7*7) == ph (verified: x/7 rounds up in fp32, *7 -> >= int)
      tx = om[n * 147 + p] * 0.1f;
      ty = om[n * 147 + 49 + p] * 0.1f;
    }
    float h = (float)ph * bin_h + rsh + ty * roi_h + (float)(s >> 2) * sub_h;
    float w = (float)pw * bin_w + rsw + tx * roi_w + (float)(s & 3) * sub_w;
    bool valid = (w >= -0.5f) && (w <= (float)WW - 0.5f) &&
                 (h >= -0.5f) && (h <= (float)HH - 0.5f);
    float hc = fminf(fmaxf(h, 0.0f), (float)(HH - 1));
    float wc = fminf(fmaxf(w, 0.0f), (float)(WW - 1));
    int h0 = (int)hc, w0 = (int)wc;
    int h1 = min(h0 + 1, HH - 1), w1i = min(w0 + 1, WW - 1);
    float lh = hc - (float)h0, lw = wc - (float)w0;
    float w00 = (1.0f - lh) * (1.0f - lw), w01 = (1.0f - lh) * lw;
    float w10 = lh * (1.0f - lw), w11 = lh * lw;
    if (!valid) { w00 = w01 = w10 = w11 = 0.0f; }
    s_c[si * 4 + 0] = { (h0 * WW + w0) * CC, w00 };
    s_c[si * 4 + 1] = { (h0 * WW + w1i) * CC, w01 };
    s_c[si * 4 + 2] = { (h1 * WW + w0) * CC, w10 };
    s_c[si * 4 + 3] = { (h1 * WW + w1i) * CC, w11 };
    s_vld[si] = valid ? 1.0f : 0.0f;
  }
  __syncthreads();
  if (tid < 49) {
    float cnt = 0.0f;
#pragma unroll
    for (int s = 0; s < 16; s++) cnt += s_vld[tid * 16 + s];
    float m = 1.0f;
    if (PASS2) {
      float mv = om[n * 147 + 98 + tid];
      m = 1.0f / (1.0f + expf(-mv));
    }
    s_scale[tid] = (cnt > 0.0f) ? m / cnt : 0.0f;
  }
  __syncthreads();

  // ---- phase 2: accumulate ----
  const int g = tid >> 7;            // wave-uniform (threads 0-127 / 128-255)
  const int c2 = (tid & 127) * 2;
  for (int p = g; p < 49; p += 2) {
    float acc0 = 0.0f, acc1 = 0.0f;
    const Corner* cp = &s_c[p * 64];
    for (int s = 0; s < 16; s++) {
      if (s_vld[p * 16 + s] == 0.0f) continue;   // wave-uniform skip
#pragma unroll
      for (int j = 0; j < 4; j++) {
        Corner cr = cp[s * 4 + j];
        f16x2 v = *(const f16x2*)(fb + cr.idx + c2);
        acc0 += cr.w * (float)v[0];
        acc1 += cr.w * (float)v[1];
      }
    }
    float sc = s_scale[p];
    float v0 = acc0 * sc, v1 = acc1 * sc;
    if (PASS2) {
      s_out[c2 * 49 + p] = v0;          // stride-49 (odd) -> conflict-free
      s_out[(c2 + 1) * 49 + p] = v1;
    } else {
      f16x2 o; o[0] = (half_t)v0; o[1] = (half_t)v1;
      *(f16x2*)(xout + (size_t)n * KDIM + p * 256 + c2) = o;   // coalesced
    }
  }

  // ---- phase 3 (PASS2): coalesced float4 write-out ----
  if (PASS2) {
    __syncthreads();
    float* ob = out + (size_t)n * KDIM;
    for (int l = tid * 4; l < KDIM; l += 1024) {
      *(float4*)(ob + l) = *(const float4*)(s_out + l);
    }
  }
}

// ---- split-K fp16 MFMA GEMM: P[z] = A(MxKc) * B(NxKc)^T, tile 64(M)x128(N), BK=64 ----
template <int SK>
__global__ __launch_bounds__(256, 4) void gemm_sk(const half_t* __restrict__ A,
                                                  const half_t* __restrict__ B,
                                                  float* __restrict__ P,
                                                  int M, int N, int K) {
  __shared__ half_t As[64 * 72];
  __shared__ half_t Bs[128 * 72];
  const int m0 = blockIdx.x * 64;
  const int n0 = blockIdx.y * 128;
  const int Kc = K / SK;
  const int kbeg = blockIdx.z * Kc;
  const int tid = threadIdx.x;
  const int lane = tid & 63;
  const int wave = tid >> 6;
  const int wm = (wave & 1) * 32;
  const int wn = (wave >> 1) * 64;
  const int lrow = tid >> 3;
  const int lcol = (tid & 7) * 8;
  const int fr = lane & 15;
  const int fk0 = (lane >> 4) * 8;
  f32x4 acc[2][4] = {};
  const half_t* Ap = A + (size_t)(m0 + lrow) * K + kbeg + lcol;
  const half_t* Bp = B + (size_t)(n0 + lrow) * K + kbeg + lcol;
  uint4 ra[2], rb[4];
  ra[0] = *(const uint4*)(Ap);
  ra[1] = *(const uint4*)(Ap + (size_t)32 * K);
#pragma unroll
  for (int p = 0; p < 4; p++) rb[p] = *(const uint4*)(Bp + (size_t)(32 * p) * K);
  const int iters = Kc >> 6;
  for (int it = 0; it < iters; it++) {
    *(uint4*)&As[lrow * 72 + lcol] = ra[0];
    *(uint4*)&As[(lrow + 32) * 72 + lcol] = ra[1];
#pragma unroll
    for (int p = 0; p < 4; p++) *(uint4*)&Bs[(lrow + 32 * p) * 72 + lcol] = rb[p];
    __syncthreads();
    if (it + 1 < iters) {
      int ko = (it + 1) * 64;
      ra[0] = *(const uint4*)(Ap + ko);
      ra[1] = *(const uint4*)(Ap + (size_t)32 * K + ko);
#pragma unroll
      for (int p = 0; p < 4; p++) rb[p] = *(const uint4*)(Bp + (size_t)(32 * p) * K + ko);
    }
#pragma unroll
    for (int ks = 0; ks < 2; ks++) {
      const int fk = fk0 + ks * 32;
      f16x8 af[2], bf[4];
      af[0] = *(const f16x8*)&As[(wm + fr) * 72 + fk];
      af[1] = *(const f16x8*)&As[(wm + 16 + fr) * 72 + fk];
#pragma unroll
      for (int j = 0; j < 4; j++) bf[j] = *(const f16x8*)&Bs[(wn + j * 16 + fr) * 72 + fk];
#pragma unroll
      for (int i = 0; i < 2; i++)
#pragma unroll
        for (int j = 0; j < 4; j++)
          acc[i][j] = __builtin_amdgcn_mfma_f32_16x16x32_f16(af[i], bf[j], acc[i][j], 0, 0, 0);
    }
    __syncthreads();
  }
  float* Pz = P + (size_t)blockIdx.z * M * N;
  const int orow = m0 + wm + (lane >> 4) * 4;
  const int ocol = n0 + wn + (lane & 15);
#pragma unroll
  for (int i = 0; i < 2; i++)
#pragma unroll
    for (int j = 0; j < 4; j++)
#pragma unroll
      for (int rr = 0; rr < 4; rr++)
        Pz[(size_t)(orow + i * 16 + rr) * N + ocol + j * 16] = acc[i][j][rr];
}

// ---- reduce SK partials + bias (+relu), write fp16 or fp32 ----
template <bool OUT16, bool RELU, int SK>
__global__ __launch_bounds__(256) void reduce_bias(const float* __restrict__ P,
                                                   const float* __restrict__ bias,
                                                   void* __restrict__ out,
                                                   int MN, int N) {
  int i = (blockIdx.x * 256 + threadIdx.x) * 4;
  if (i >= MN) return;
  float4 s = *(const float4*)(P + i);
#pragma unroll
  for (int z = 1; z < SK; z++) {
    float4 t = *(const float4*)(P + (size_t)z * MN + i);
    s.x += t.x; s.y += t.y; s.z += t.z; s.w += t.w;
  }
  float4 bv = *(const float4*)(bias + (i & (N - 1)));
  s.x += bv.x; s.y += bv.y; s.z += bv.z; s.w += bv.w;
  if (RELU) {
    s.x = fmaxf(s.x, 0.0f); s.y = fmaxf(s.y, 0.0f);
    s.z = fmaxf(s.z, 0.0f); s.w = fmaxf(s.w, 0.0f);
  }
  if (OUT16) {
    f16x4 o;
    o[0] = (half_t)s.x; o[1] = (half_t)s.y; o[2] = (half_t)s.z; o[3] = (half_t)s.w;
    *(f16x4*)((half_t*)out + i) = o;
  } else {
    *(float4*)((float*)out + i) = s;
  }
}

// ---------------- fp32 GEMM3: om(N,147) = h2(N,1024) @ w3(147,1024)^T + b3 ----------------
__global__ __launch_bounds__(192) void gemm_small(const float* __restrict__ h2,
                                                  const float* __restrict__ w3,
                                                  const float* __restrict__ b3,
                                                  float* __restrict__ om) {
  __shared__ float hs[FC];
  int n = blockIdx.x;
  for (int k = threadIdx.x; k < FC; k += 192) hs[k] = h2[(size_t)n * FC + k];
  __syncthreads();
  int j = threadIdx.x;
  if (j < 147) {
    float acc = b3[j];
    const float* wr = w3 + (size_t)j * FC;
    for (int k = 0; k < FC; k += 4) {
      float4 wv = *(const float4*)(wr + k);
      acc += hs[k] * wv.x + hs[k + 1] * wv.y + hs[k + 2] * wv.z + hs[k + 3] * wv.w;
    }
    om[n * 147 + j] = acc;
  }
}

extern "C" void kernel_launch(void* const* d_in, const int* in_sizes, int n_in,
                              void* d_out, int out_size, void* d_ws, size_t ws_size,
                              hipStream_t stream) {
  const float* feat = (const float*)d_in[0];
  const float* rois = (const float*)d_in[1];
  const float* w1 = (const float*)d_in[2];
  const float* b1 = (const float*)d_in[3];
  const float* w2 = (const float*)d_in[4];
  const float* b2 = (const float*)d_in[5];
  const float* w3 = (const float*)d_in[6];
  const float* b3 = (const float*)d_in[7];
  float* out = (float*)d_out;
  char* ws = (char*)d_ws;

  // workspace carve (~83.7 MB total)
  half_t* featT = (half_t*)ws;                        // 10,240,000 B
  half_t* xh    = (half_t*)(ws + 10240000);           // 12,845,056 B
  half_t* w1p   = (half_t*)(ws + 23085056);           // 25,690,112 B
  half_t* w2h   = (half_t*)(ws + 48775168);           //  2,097,152 B
  half_t* h1    = (half_t*)(ws + 50872320);           //  1,048,576 B
  float*  h2    = (float*)(ws + 51920896);            //  2,097,152 B
  float*  omb   = (float*)(ws + 54018048);            //    301,056 B
  float*  part  = (float*)(ws + 54319104);            // 29,360,128 B

  const int MN = NROI * FC;  // 524288

  transpose_feat<<<dim3(313, 8, 2), dim3(32, 8), 0, stream>>>(feat, featT);
  permute_w1<<<dim3(1024), dim3(256), 0, stream>>>(w1, w1p);
  convert_f32_f16<<<dim3(1024), dim3(256), 0, stream>>>(w2, w2h, FC * FC);
  pool_kernel<false><<<dim3(NROI), dim3(256), 0, stream>>>(featT, rois, nullptr, xh, nullptr);

  // GEMM1: (512x12544) @ (1024x12544)^T -> SK=14, 896 blocks
  gemm_sk<14><<<dim3(8, 8, 14), dim3(256), 0, stream>>>(xh, w1p, part, NROI, FC, KDIM);
  reduce_bias<true, true, 14><<<dim3(MN / 1024), dim3(256), 0, stream>>>(part, b1, (void*)h1, MN, FC);

  // GEMM2: (512x1024) @ (1024x1024)^T -> SK=8, 512 blocks
  gemm_sk<8><<<dim3(8, 8, 8), dim3(256), 0, stream>>>(h1, w2h, part, NROI, FC, FC);
  reduce_bias<false, true, 8><<<dim3(MN / 1024), dim3(256), 0, stream>>>(part, b2, (void*)h2, MN, FC);

  gemm_small<<<dim3(NROI), dim3(192), 0, stream>>>(h2, w3, b3, omb);
  pool_kernel<true><<<dim3(NROI), dim3(256), 0, stream>>>(featT, rois, omb, nullptr, out);
}

// Round 4
// 404.383 us; speedup vs baseline: 1.4640x; 1.4640x over previous
//
#include <hip/hip_runtime.h>

// Problem constants (fixed by setup_inputs)
#define BB 2
#define CC 256
#define HH 100
#define WW 100
#define NROI 512
#define KDIM 12544   // 49*256
#define FC 1024

typedef _Float16 half_t;
typedef _Float16 f16x2 __attribute__((ext_vector_type(2)));
typedef _Float16 f16x8 __attribute__((ext_vector_type(8)));
typedef _Float16 f16x4 __attribute__((ext_vector_type(4)));
typedef float f32x4 __attribute__((ext_vector_type(4)));

// ---------------- feat (B,C,H,W) fp32 -> featT (B,H*W,C) fp16 ----------------
__global__ __launch_bounds__(256) void transpose_feat(const float* __restrict__ feat,
                                                      half_t* __restrict__ featT) {
  __shared__ float tile[32][33];
  int b = blockIdx.z;
  int hw0 = blockIdx.x * 32;
  int c0 = blockIdx.y * 32;
  int tx = threadIdx.x, ty = threadIdx.y;
  const float* fb = feat + (size_t)b * CC * (HH * WW);
#pragma unroll
  for (int i = 0; i < 4; i++) {
    int c = c0 + ty + i * 8;
    int hw = hw0 + tx;
    tile[ty + i * 8][tx] = (hw < HH * WW) ? fb[(size_t)c * (HH * WW) + hw] : 0.0f;
  }
  __syncthreads();
  half_t* ob = featT + (size_t)b * (HH * WW) * CC;
#pragma unroll
  for (int i = 0; i < 4; i++) {
    int hw = hw0 + ty + i * 8;
    int c = c0 + tx;
    if (hw < HH * WW) ob[(size_t)hw * CC + c] = (half_t)tile[tx][ty + i * 8];
  }
}

// ---------------- fp32 -> fp16 convert (w1, w2) ----------------
__global__ __launch_bounds__(256) void convert_f32_f16(const float* __restrict__ in,
                                                       half_t* __restrict__ out, int n) {
  int i4 = (blockIdx.x * 256 + threadIdx.x) * 4;
  if (i4 < n) {
    float4 v = *(const float4*)(in + i4);
    f16x4 o;
    o[0] = (half_t)v.x; o[1] = (half_t)v.y; o[2] = (half_t)v.z; o[3] = (half_t)v.w;
    *(f16x4*)(out + i4) = o;
  }
}

// ---------------- deformable PSROI pooling, one block (512 thr) per ROI ----------------
// Phase 1: 49 bins x 16 samples -> 4 (idx, weight) corners into LDS (zero weight if
//          invalid -> NO branch in the hot loop).
// Phase 2: wave per bin; lane owns 4 channels (f16x4 8B gathers = 512B/wave/pixel).
//          Corner metadata readfirstlane'd to SGPRs (uniform by construction).
// Phase 3: LDS-staged output so global writes are wide & coalesced.
//          PASS1 writes x fp16 in w1's NATIVE k=c*49+p layout (no w1 permute needed).
template <bool PASS2>
__global__ __launch_bounds__(512) void pool_kernel(const half_t* __restrict__ featT,
                                                   const float* __restrict__ rois,
                                                   const float* __restrict__ om,
                                                   half_t* __restrict__ xout,
                                                   float* __restrict__ out) {
  struct Corner { int idx; float w; };
  __shared__ Corner s_c[784 * 4];                     // 25088 B
  __shared__ float s_vld[784];                        //  3136 B
  __shared__ float s_scale[49];
  __shared__ float  s_outf[PASS2 ? KDIM : 1];         // 50176 B (PASS2)
  __shared__ half_t s_outh[PASS2 ? 1 : KDIM];         // 25088 B (PASS1)

  const int n = blockIdx.x;
  const int tid = threadIdx.x;
  const float* r = rois + n * 5;
  const int b = (int)r[0];
  const float rsw = rintf(r[1]) * 0.0625f - 0.5f;     // rintf = round-half-even = jnp.round
  const float rsh = rintf(r[2]) * 0.0625f - 0.5f;
  const float rew = (rintf(r[3]) + 1.0f) * 0.0625f - 0.5f;
  const float reh = (rintf(r[4]) + 1.0f) * 0.0625f - 0.5f;
  const float roi_w = fmaxf(rew - rsw, 0.1f);
  const float roi_h = fmaxf(reh - rsh, 0.1f);
  const float bin_h = roi_h / 7.0f, bin_w = roi_w / 7.0f;
  const float sub_h = bin_h * 0.25f, sub_w = bin_w * 0.25f;
  const half_t* fb = featT + (size_t)b * (HH * WW) * CC;

  // ---- phase 1: sample metadata ----
  for (int si = tid; si < 784; si += 512) {
    int p = si >> 4, s = si & 15;
    int ph = p / 7, pw = p - ph * 7;
    float tx = 0.0f, ty = 0.0f;
    if (PASS2) {
      // part_h = floor(ph/7*7) == ph in fp32 (verified)
      tx = om[n * 147 + p] * 0.1f;
      ty = om[n * 147 + 49 + p] * 0.1f;
    }
    float h = (float)ph * bin_h + rsh + ty * roi_h + (float)(s >> 2) * sub_h;
    float w = (float)pw * bin_w + rsw + tx * roi_w + (float)(s & 3) * sub_w;
    bool valid = (w >= -0.5f) && (w <= (float)WW - 0.5f) &&
                 (h >= -0.5f) && (h <= (float)HH - 0.5f);
    float hc = fminf(fmaxf(h, 0.0f), (float)(HH - 1));
    float wc = fminf(fmaxf(w, 0.0f), (float)(WW - 1));
    int h0 = (int)hc, w0 = (int)wc;
    int h1 = min(h0 + 1, HH - 1), w1i = min(w0 + 1, WW - 1);
    float lh = hc - (float)h0, lw = wc - (float)w0;
    float w00 = (1.0f - lh) * (1.0f - lw), w01 = (1.0f - lh) * lw;
    float w10 = lh * (1.0f - lw), w11 = lh * lw;
    if (!valid) { w00 = w01 = w10 = w11 = 0.0f; }
    s_c[si * 4 + 0] = { (h0 * WW + w0) * CC, w00 };
    s_c[si * 4 + 1] = { (h0 * WW + w1i) * CC, w01 };
    s_c[si * 4 + 2] = { (h1 * WW + w0) * CC, w10 };
    s_c[si * 4 + 3] = { (h1 * WW + w1i) * CC, w11 };
    s_vld[si] = valid ? 1.0f : 0.0f;
  }
  __syncthreads();
  if (tid < 49) {
    float cnt = 0.0f;
#pragma unroll
    for (int s = 0; s < 16; s++) cnt += s_vld[tid * 16 + s];
    float m = 1.0f;
    if (PASS2) {
      float mv = om[n * 147 + 98 + tid];
      m = 1.0f / (1.0f + expf(-mv));
    }
    s_scale[tid] = (cnt > 0.0f) ? m / cnt : 0.0f;
  }
  __syncthreads();

  // ---- phase 2: accumulate (wave per bin, lane = 4 channels) ----
  const int wv = tid >> 6;          // 0..7, wave-uniform
  const int c4 = (tid & 63) * 4;
  for (int p = wv; p < 49; p += 8) {
    float a0 = 0.0f, a1 = 0.0f, a2 = 0.0f, a3 = 0.0f;
    const Corner* cp = &s_c[p * 64];
#pragma unroll 8
    for (int q = 0; q < 64; q++) {            // 16 samples x 4 corners, branch-free
      Corner cr = cp[q];
      int sidx = __builtin_amdgcn_readfirstlane(cr.idx);          // uniform -> SGPR
      float sw = __uint_as_float(__builtin_amdgcn_readfirstlane(__float_as_uint(cr.w)));
      f16x4 v = *(const f16x4*)(fb + sidx + c4);                  // sgpr base + const voffset
      a0 += sw * (float)v[0];   // v_fma_mix
      a1 += sw * (float)v[1];
      a2 += sw * (float)v[2];
      a3 += sw * (float)v[3];
    }
    float sc = s_scale[p];
    a0 *= sc; a1 *= sc; a2 *= sc; a3 *= sc;
    if (PASS2) {
      s_outf[(c4 + 0) * 49 + p] = a0;
      s_outf[(c4 + 1) * 49 + p] = a1;
      s_outf[(c4 + 2) * 49 + p] = a2;
      s_outf[(c4 + 3) * 49 + p] = a3;
    } else {
      s_outh[(c4 + 0) * 49 + p] = (half_t)a0;
      s_outh[(c4 + 1) * 49 + p] = (half_t)a1;
      s_outh[(c4 + 2) * 49 + p] = (half_t)a2;
      s_outh[(c4 + 3) * 49 + p] = (half_t)a3;
    }
  }
  __syncthreads();

  // ---- phase 3: coalesced write-out ----
  if (PASS2) {
    float* ob = out + (size_t)n * KDIM;
    for (int l = tid * 4; l < KDIM; l += 2048)
      *(float4*)(ob + l) = *(const float4*)(s_outf + l);
  } else {
    half_t* ob = xout + (size_t)n * KDIM;        // layout k = c*49+p (w1-native)
    for (int l = tid * 8; l < KDIM; l += 4096)
      *(f16x8*)(ob + l) = *(const f16x8*)(s_outh + l);
  }
}

// ---- split-K fp16 MFMA GEMM: P[z] = A(MxKc) * B(NxKc)^T, tile 64(M)x128(N), BK=64 ----
template <int SK>
__global__ __launch_bounds__(256, 4) void gemm_sk(const half_t* __restrict__ A,
                                                  const half_t* __restrict__ B,
                                                  float* __restrict__ P,
                                                  int M, int N, int K) {
  __shared__ half_t As[64 * 72];
  __shared__ half_t Bs[128 * 72];
  const int m0 = blockIdx.x * 64;
  const int n0 = blockIdx.y * 128;
  const int Kc = K / SK;
  const int kbeg = blockIdx.z * Kc;
  const int tid = threadIdx.x;
  const int lane = tid & 63;
  const int wave = tid >> 6;
  const int wm = (wave & 1) * 32;
  const int wn = (wave >> 1) * 64;
  const int lrow = tid >> 3;
  const int lcol = (tid & 7) * 8;
  const int fr = lane & 15;
  const int fk0 = (lane >> 4) * 8;
  f32x4 acc[2][4] = {};
  const half_t* Ap = A + (size_t)(m0 + lrow) * K + kbeg + lcol;
  const half_t* Bp = B + (size_t)(n0 + lrow) * K + kbeg + lcol;
  uint4 ra[2], rb[4];
  ra[0] = *(const uint4*)(Ap);
  ra[1] = *(const uint4*)(Ap + (size_t)32 * K);
#pragma unroll
  for (int p = 0; p < 4; p++) rb[p] = *(const uint4*)(Bp + (size_t)(32 * p) * K);
  const int iters = Kc >> 6;
  for (int it = 0; it < iters; it++) {
    *(uint4*)&As[lrow * 72 + lcol] = ra[0];
    *(uint4*)&As[(lrow + 32) * 72 + lcol] = ra[1];
#pragma unroll
    for (int p = 0; p < 4; p++) *(uint4*)&Bs[(lrow + 32 * p) * 72 + lcol] = rb[p];
    __syncthreads();
    if (it + 1 < iters) {
      int ko = (it + 1) * 64;
      ra[0] = *(const uint4*)(Ap + ko);
      ra[1] = *(const uint4*)(Ap + (size_t)32 * K + ko);
#pragma unroll
      for (int p = 0; p < 4; p++) rb[p] = *(const uint4*)(Bp + (size_t)(32 * p) * K + ko);
    }
#pragma unroll
    for (int ks = 0; ks < 2; ks++) {
      const int fk = fk0 + ks * 32;
      f16x8 af[2], bf[4];
      af[0] = *(const f16x8*)&As[(wm + fr) * 72 + fk];
      af[1] = *(const f16x8*)&As[(wm + 16 + fr) * 72 + fk];
#pragma unroll
      for (int j = 0; j < 4; j++) bf[j] = *(const f16x8*)&Bs[(wn + j * 16 + fr) * 72 + fk];
#pragma unroll
      for (int i = 0; i < 2; i++)
#pragma unroll
        for (int j = 0; j < 4; j++)
          acc[i][j] = __builtin_amdgcn_mfma_f32_16x16x32_f16(af[i], bf[j], acc[i][j], 0, 0, 0);
    }
    __syncthreads();
  }
  float* Pz = P + (size_t)blockIdx.z * M * N;
  const int orow = m0 + wm + (lane >> 4) * 4;
  const int ocol = n0 + wn + (lane & 15);
#pragma unroll
  for (int i = 0; i < 2; i++)
#pragma unroll
    for (int j = 0; j < 4; j++)
#pragma unroll
      for (int rr = 0; rr < 4; rr++)
        Pz[(size_t)(orow + i * 16 + rr) * N + ocol + j * 16] = acc[i][j][rr];
}

// ---- reduce SK partials + bias (+relu), write fp16 or fp32 ----
template <bool OUT16, bool RELU, int SK>
__global__ __launch_bounds__(256) void reduce_bias(const float* __restrict__ P,
                                                   const float* __restrict__ bias,
                                                   void* __restrict__ out,
                                                   int MN, int N) {
  int i = (blockIdx.x * 256 + threadIdx.x) * 4;
  if (i >= MN) return;
  float4 s = *(const float4*)(P + i);
#pragma unroll
  for (int z = 1; z < SK; z++) {
    float4 t = *(const float4*)(P + (size_t)z * MN + i);
    s.x += t.x; s.y += t.y; s.z += t.z; s.w += t.w;
  }
  float4 bv = *(const float4*)(bias + (i & (N - 1)));
  s.x += bv.x; s.y += bv.y; s.z += bv.z; s.w += bv.w;
  if (RELU) {
    s.x = fmaxf(s.x, 0.0f); s.y = fmaxf(s.y, 0.0f);
    s.z = fmaxf(s.z, 0.0f); s.w = fmaxf(s.w, 0.0f);
  }
  if (OUT16) {
    f16x4 o;
    o[0] = (half_t)s.x; o[1] = (half_t)s.y; o[2] = (half_t)s.z; o[3] = (half_t)s.w;
    *(f16x4*)((half_t*)out + i) = o;
  } else {
    *(float4*)((float*)out + i) = s;
  }
}

// ---------------- fp32 GEMM3: om(N,147) = h2(N,1024) @ w3(147,1024)^T + b3 ----------------
__global__ __launch_bounds__(192) void gemm_small(const float* __restrict__ h2,
                                                  const float* __restrict__ w3,
                                                  const float* __restrict__ b3,
                                                  float* __restrict__ om) {
  __shared__ float hs[FC];
  int n = blockIdx.x;
  for (int k = threadIdx.x; k < FC; k += 192) hs[k] = h2[(size_t)n * FC + k];
  __syncthreads();
  int j = threadIdx.x;
  if (j < 147) {
    float acc = b3[j];
    const float* wr = w3 + (size_t)j * FC;
    for (int k = 0; k < FC; k += 4) {
      float4 wv = *(const float4*)(wr + k);
      acc += hs[k] * wv.x + hs[k + 1] * wv.y + hs[k + 2] * wv.z + hs[k + 3] * wv.w;
    }
    om[n * 147 + j] = acc;
  }
}

extern "C" void kernel_launch(void* const* d_in, const int* in_sizes, int n_in,
                              void* d_out, int out_size, void* d_ws, size_t ws_size,
                              hipStream_t stream) {
  const float* feat = (const float*)d_in[0];
  const float* rois = (const float*)d_in[1];
  const float* w1 = (const float*)d_in[2];
  const float* b1 = (const float*)d_in[3];
  const float* w2 = (const float*)d_in[4];
  const float* b2 = (const float*)d_in[5];
  const float* w3 = (const float*)d_in[6];
  const float* b3 = (const float*)d_in[7];
  float* out = (float*)d_out;
  char* ws = (char*)d_ws;

  // workspace carve (~83.7 MB total)
  half_t* featT = (half_t*)ws;                        // 10,240,000 B
  half_t* xh    = (half_t*)(ws + 10240000);           // 12,845,056 B  (k = c*49+p)
  half_t* w1h   = (half_t*)(ws + 23085056);           // 25,690,112 B  (raw layout)
  half_t* w2h   = (half_t*)(ws + 48775168);           //  2,097,152 B
  half_t* h1    = (half_t*)(ws + 50872320);           //  1,048,576 B
  float*  h2    = (float*)(ws + 51920896);            //  2,097,152 B
  float*  omb   = (float*)(ws + 54018048);            //    301,056 B
  float*  part  = (float*)(ws + 54319104);            // 29,360,128 B

  const int MN = NROI * FC;  // 524288

  transpose_feat<<<dim3(313, 8, 2), dim3(32, 8), 0, stream>>>(feat, featT);
  convert_f32_f16<<<dim3(12544), dim3(256), 0, stream>>>(w1, w1h, FC * KDIM);
  convert_f32_f16<<<dim3(1024), dim3(256), 0, stream>>>(w2, w2h, FC * FC);
  pool_kernel<false><<<dim3(NROI), dim3(512), 0, stream>>>(featT, rois, nullptr, xh, nullptr);

  // GEMM1: (512x12544) @ (1024x12544)^T -> SK=14, 896 blocks
  gemm_sk<14><<<dim3(8, 8, 14), dim3(256), 0, stream>>>(xh, w1h, part, NROI, FC, KDIM);
  reduce_bias<true, true, 14><<<dim3(MN / 1024), dim3(256), 0, stream>>>(part, b1, (void*)h1, MN, FC);

  // GEMM2: (512x1024) @ (1024x1024)^T -> SK=8, 512 blocks
  gemm_sk<8><<<dim3(8, 8, 8), dim3(256), 0, stream>>>(h1, w2h, part, NROI, FC, FC);
  reduce_bias<false, true, 8><<<dim3(MN / 1024), dim3(256), 0, stream>>>(part, b2, (void*)h2, MN, FC);

  gemm_small<<<dim3(NROI), dim3(192), 0, stream>>>(h2, w3, b3, omb);
  pool_kernel<true><<<dim3(NROI), dim3(512), 0, stream>>>(featT, rois, omb, nullptr, out);
}